// Round 6
// baseline (721.544 us; speedup 1.0000x reference)
//
#include <hip/hip_runtime.h>
#include <hip/hip_bf16.h>
#include <math.h>

#define NSPANS 16384
#define CC     16
#define DIM    300
#define DSPAN  512
#define HH     150
#define HP     160     // padded H
#define DMENT  812     // DSPAN + DIM
#define KP     320     // padded K for candidate GEMM (300 -> 320)

typedef short bf16x8 __attribute__((ext_vector_type(8)));
typedef float f32x4  __attribute__((ext_vector_type(4)));

__device__ __forceinline__ unsigned short f2bf(float f) {
    union { float f; unsigned int u; } v; v.f = f;
    unsigned int r = (v.u + 0x7FFFu + ((v.u >> 16) & 1u)) >> 16;   // RNE (no NaN inputs)
    return (unsigned short)r;
}

// ---------------------------------------------------------------------------
// Kernel 0 (prep, every call): W1_bot [300x150] f32  ->  Wt [160x320] bf16,
// transposed (n-major, k-contiguous), zero-padded. 51200 elems.
// ---------------------------------------------------------------------------
__global__ __launch_bounds__(256) void k0_prep(const float* __restrict__ W1,
                                               unsigned short* __restrict__ Wt) {
    int idx = blockIdx.x * 256 + threadIdx.x;          // 200 blocks -> exactly 51200
    int n = idx / KP, k = idx - n * KP;
    float v = (n < HH && k < DIM) ? W1[(size_t)(DSPAN + k) * HH + n] : 0.f;
    Wt[idx] = f2bf(v);
}

// ---------------------------------------------------------------------------
// Kernel 1: per 16 spans -- copy sv into out[0:512], hs = sv@W1_top + b1
// stashed into out[n][512+j] (overwritten later by kernel 2). fp32 exact.
// ---------------------------------------------------------------------------
__global__ __launch_bounds__(256) void k1_span(const float* __restrict__ sv,
                                               const float* __restrict__ W1,
                                               const float* __restrict__ b1,
                                               float* __restrict__ out) {
    const int b  = blockIdx.x;     // 1024 blocks
    const int t  = threadIdx.x;
    const int n0 = b * 16;

    __shared__ float svc[16][36];
    __shared__ float w1c[32][HP];

    #pragma unroll
    for (int i = 0; i < 8; ++i) {
        int idx4 = t + i * 256;
        int r    = idx4 >> 7;
        int c4   = idx4 & 127;
        float4 v = *(const float4*)(sv + (size_t)(n0 + r) * DSPAN + c4 * 4);
        *(float4*)(out + (size_t)(n0 + r) * DMENT + c4 * 4) = v;
    }

    const int tc = t & 15;
    const int tr = t >> 4;
    const int j0 = tc * 10;

    float acc[10];
    #pragma unroll
    for (int j = 0; j < 10; ++j) acc[j] = 0.f;

    for (int k0 = 0; k0 < DSPAN; k0 += 32) {
        __syncthreads();
        {
            int idx = t * 2;
            int r = idx >> 5, kk = idx & 31;
            float2 v = *(const float2*)(sv + (size_t)(n0 + r) * DSPAN + k0 + kk);
            svc[r][kk]     = v.x;
            svc[r][kk + 1] = v.y;
        }
        #pragma unroll
        for (int i = 0; i < 20; ++i) {
            int idx = t + i * 256;
            int k = idx / HP, j = idx % HP;
            w1c[k][j] = (j < HH) ? W1[(size_t)(k0 + k) * HH + j] : 0.f;
        }
        __syncthreads();
        #pragma unroll
        for (int kk = 0; kk < 32; ++kk) {
            float a = svc[tr][kk];
            #pragma unroll
            for (int j = 0; j < 10; ++j)
                acc[j] += a * w1c[kk][j0 + j];
        }
    }

    #pragma unroll
    for (int j = 0; j < 10; ++j) {
        int jj = j0 + j;
        if (jj < HH)
            out[(size_t)(n0 + tr) * DMENT + DSPAN + jj] = acc[j] + b1[jj];
    }
}

// ---------------------------------------------------------------------------
// Kernel 2 (MFMA): per 4 spans (64 candidate rows).
//   A = gathered emb rows -> bf16 LDS [64][72-pad]
//   B = Wt (pre-transposed bf16 W1_bot) -> LDS [160][72-pad]
//   acc[64x160] = A@B via mfma_f32_16x16x32_bf16 (wave w owns span w's 16 rows)
//   score = relu(acc + hs).W2, masked softmax, weighted emb sum (fp32 exact).
// k-mapping k=(lane>>4)*8+i applied identically to A and B fragments
// (permutation-invariant); C/D: col=lane&15, row=(lane>>4)*4+reg [m89-verified].
// ---------------------------------------------------------------------------
__global__ __launch_bounds__(256) void k2_mfma(const int*   __restrict__ cand,
                                               const float* __restrict__ mask,
                                               const float* __restrict__ emb,
                                               const unsigned short* __restrict__ Wt,
                                               const float* __restrict__ W2,
                                               float*       __restrict__ out) {
    const int b  = blockIdx.x;     // 4096 blocks
    const int t  = threadIdx.x;
    const int n0 = b * 4;
    const int w  = t >> 6;         // wave = span within block
    const int l  = t & 63;
    const int sp = l & 15;         // spatial index (A row / B col within tile)
    const int g  = l >> 4;         // k-group

    __shared__ unsigned short A_lds[64][72];    // pad 64->72 shorts (144 B rows)
    __shared__ unsigned short B_lds[160][72];
    __shared__ float hsL[4][HP];
    __shared__ float w2L[HP];
    __shared__ int   candL[64];
    __shared__ float maskL[64];
    __shared__ float scoresL[64];
    __shared__ float pL[64];

    if (t < 64) {
        candL[t] = cand[n0 * CC + t];
        maskL[t] = mask[n0 * CC + t];
    }
    #pragma unroll
    for (int i = 0; i < 3; ++i) {
        int idx = t + i * 256;
        if (idx < 4 * HP) {
            int s = idx / HP, j = idx - s * HP;
            hsL[s][j] = (j < HH) ? out[(size_t)(n0 + s) * DMENT + DSPAN + j] : 0.f;
        }
    }
    if (t < HP) w2L[t] = (t < HH) ? W2[t] : 0.f;
    __syncthreads();

    f32x4 acc[10];
    #pragma unroll
    for (int i = 0; i < 10; ++i) acc[i] = 0.f;

    for (int k0 = 0; k0 < KP; k0 += 64) {
        __syncthreads();
        // ---- stage A: row r = t>>2 (64 rows), q = t&3 covers k0+q*16 .. +16
        {
            int r = t >> 2, q = t & 3;
            int base = k0 + q * 16;
            const float* src = emb + (size_t)candL[r] * DIM + base;
            unsigned short tmp[16];
            if (base + 16 <= DIM) {
                #pragma unroll
                for (int i2 = 0; i2 < 4; ++i2) {
                    float4 v = *(const float4*)(src + i2 * 4);
                    tmp[i2 * 4 + 0] = f2bf(v.x);
                    tmp[i2 * 4 + 1] = f2bf(v.y);
                    tmp[i2 * 4 + 2] = f2bf(v.z);
                    tmp[i2 * 4 + 3] = f2bf(v.w);
                }
            } else {
                #pragma unroll
                for (int i2 = 0; i2 < 16; ++i2) {
                    int kg = base + i2;
                    tmp[i2] = (kg < DIM) ? f2bf(src[i2]) : (unsigned short)0;
                }
            }
            uint4 p0, p1;
            p0.x = tmp[0]  | (tmp[1]  << 16);
            p0.y = tmp[2]  | (tmp[3]  << 16);
            p0.z = tmp[4]  | (tmp[5]  << 16);
            p0.w = tmp[6]  | (tmp[7]  << 16);
            p1.x = tmp[8]  | (tmp[9]  << 16);
            p1.y = tmp[10] | (tmp[11] << 16);
            p1.z = tmp[12] | (tmp[13] << 16);
            p1.w = tmp[14] | (tmp[15] << 16);
            *(uint4*)&A_lds[r][q * 16]     = p0;
            *(uint4*)&A_lds[r][q * 16 + 8] = p1;
        }
        // ---- stage B: 160 rows x 64 k = 1280 16B segments, 5 per thread
        #pragma unroll
        for (int i2 = 0; i2 < 5; ++i2) {
            int idx = t + i2 * 256;
            int row = idx >> 3, seg = idx & 7;
            uint4 v = *(const uint4*)(Wt + (size_t)row * KP + k0 + seg * 8);
            *(uint4*)&B_lds[row][seg * 8] = v;
        }
        __syncthreads();
        // ---- MFMA: wave w -> A rows [16w, 16w+16), all 10 n-tiles
        #pragma unroll
        for (int ks = 0; ks < 2; ++ks) {
            int koff = ks * 32 + g * 8;
            bf16x8 af = *(const bf16x8*)&A_lds[w * 16 + sp][koff];
            #pragma unroll
            for (int nt = 0; nt < 10; ++nt) {
                bf16x8 bfr = *(const bf16x8*)&B_lds[nt * 16 + sp][koff];
                acc[nt] = __builtin_amdgcn_mfma_f32_16x16x32_bf16(af, bfr, acc[nt], 0, 0, 0);
            }
        }
    }

    // ---- scores: relu(acc + hs) . W2
    // lane holds rows m = g*4 + r (r=0..3) at cols nt*16+sp
    float part0 = 0.f, part1 = 0.f, part2 = 0.f, part3 = 0.f;
    #pragma unroll
    for (int nt = 0; nt < 10; ++nt) {
        int col = nt * 16 + sp;
        float hb  = hsL[w][col];
        float w2v = w2L[col];
        part0 += fmaxf(acc[nt][0] + hb, 0.f) * w2v;
        part1 += fmaxf(acc[nt][1] + hb, 0.f) * w2v;
        part2 += fmaxf(acc[nt][2] + hb, 0.f) * w2v;
        part3 += fmaxf(acc[nt][3] + hb, 0.f) * w2v;
    }
    #pragma unroll
    for (int m = 1; m < 16; m <<= 1) {
        part0 += __shfl_xor(part0, m, 64);
        part1 += __shfl_xor(part1, m, 64);
        part2 += __shfl_xor(part2, m, 64);
        part3 += __shfl_xor(part3, m, 64);
    }
    if (sp == 0) {
        scoresL[w * 16 + g * 4 + 0] = part0;
        scoresL[w * 16 + g * 4 + 1] = part1;
        scoresL[w * 16 + g * 4 + 2] = part2;
        scoresL[w * 16 + g * 4 + 3] = part3;
    }
    __syncthreads();

    // ---- masked softmax over 16 candidates per span (first wave)
    if (t < 64) {
        float v = (maskL[t] > 0.f) ? scoresL[t] : -INFINITY;
        float mx = v;
        #pragma unroll
        for (int m = 1; m < 16; m <<= 1) mx = fmaxf(mx, __shfl_xor(mx, m, 64));
        float e = expf(v - mx);
        float sm = e;
        #pragma unroll
        for (int m = 1; m < 16; m <<= 1) sm += __shfl_xor(sm, m, 64);
        pL[t] = e / sm;
    }
    __syncthreads();

    // ---- weighted sum of candidate embeddings (fp32 exact) + store
    for (int idx = t; idx < 4 * DIM; idx += 256) {
        int s = idx / DIM, d = idx - s * DIM;
        float a = 0.f;
        #pragma unroll
        for (int c = 0; c < CC; ++c)
            a += pL[s * CC + c] * emb[(size_t)candL[s * CC + c] * DIM + d];
        out[(size_t)(n0 + s) * DMENT + DSPAN + d] = a;
    }
}

extern "C" void kernel_launch(void* const* d_in, const int* in_sizes, int n_in,
                              void* d_out, int out_size, void* d_ws, size_t ws_size,
                              hipStream_t stream) {
    const float* sv   = (const float*)d_in[0];
    const int*   cand = (const int*)d_in[1];
    const float* mask = (const float*)d_in[2];
    const float* emb  = (const float*)d_in[3];
    const float* W1   = (const float*)d_in[4];
    const float* b1   = (const float*)d_in[5];
    const float* W2   = (const float*)d_in[6];
    // b2 (d_in[7]) is softmax-invariant -> dropped
    float* out = (float*)d_out;
    unsigned short* Wt = (unsigned short*)d_ws;   // 160*320*2 = 102400 B

    k0_prep<<<(HP * KP) / 256, 256, 0, stream>>>(W1, Wt);
    k1_span<<<NSPANS / 16, 256, 0, stream>>>(sv, W1, b1, out);
    k2_mfma<<<NSPANS / 4, 256, 0, stream>>>(cand, mask, emb, Wt, W2, out);
}

// Round 7
// 659.309 us; speedup vs baseline: 1.0944x; 1.0944x over previous
//
#include <hip/hip_runtime.h>
#include <hip/hip_bf16.h>
#include <math.h>

#define NSPANS 16384
#define CC     16
#define DIM    300
#define DSPAN  512
#define HH     150
#define HP     160     // padded H
#define DMENT  812     // DSPAN + DIM
#define KP     320     // padded K for candidate GEMM (300 -> 320)

typedef short bf16x8 __attribute__((ext_vector_type(8)));
typedef float f32x4  __attribute__((ext_vector_type(4)));

__device__ __forceinline__ unsigned short f2bf(float f) {
    union { float f; unsigned int u; } v; v.f = f;
    unsigned int r = (v.u + 0x7FFFu + ((v.u >> 16) & 1u)) >> 16;   // RNE (no NaN inputs)
    return (unsigned short)r;
}

// ---------------------------------------------------------------------------
// Kernel 0 (prep): W1_bot [300x150] f32 -> Wt [160x320] bf16 transposed.
// ---------------------------------------------------------------------------
__global__ __launch_bounds__(256) void k0_prep(const float* __restrict__ W1,
                                               unsigned short* __restrict__ Wt) {
    int idx = blockIdx.x * 256 + threadIdx.x;          // 200 blocks = 51200
    int n = idx / KP, k = idx - n * KP;
    float v = (n < HH && k < DIM) ? W1[(size_t)(DSPAN + k) * HH + n] : 0.f;
    Wt[idx] = f2bf(v);
}

// ---------------------------------------------------------------------------
// Kernel 1 (v2): 32 spans/block, 512 blocks. acc[4][5] register tile:
// each w1c read feeds 4 FMAs; A-read is a broadcast ds_read_b128 from
// k-major svc_t. K-accumulation order (k0 asc, kk asc) identical to the
// validated version -> hs bit-identical.
// ---------------------------------------------------------------------------
__global__ __launch_bounds__(256) void k1_span(const float* __restrict__ sv,
                                               const float* __restrict__ W1,
                                               const float* __restrict__ b1,
                                               float* __restrict__ out) {
    const int b  = blockIdx.x;     // 512 blocks
    const int t  = threadIdx.x;
    const int n0 = b * 32;

    __shared__ float svc_t[32][36];   // [k][row], pad 32->36
    __shared__ float w1c[32][HP];

    // copy sv -> out: 32 rows x 128 float4, 16 per thread
    #pragma unroll
    for (int i = 0; i < 16; ++i) {
        int idx4 = t + i * 256;
        int r = idx4 >> 7, c4 = idx4 & 127;
        float4 v = *(const float4*)(sv + (size_t)(n0 + r) * DSPAN + c4 * 4);
        *(float4*)(out + (size_t)(n0 + r) * DMENT + c4 * 4) = v;
    }

    const int tc = t & 31;          // 32 col groups x 5 cols
    const int tr = t >> 5;          // 8 row groups x 4 rows
    const int j0 = tc * 5;
    const int r0 = tr * 4;

    float acc[4][5];
    #pragma unroll
    for (int i = 0; i < 4; ++i)
        #pragma unroll
        for (int j = 0; j < 5; ++j) acc[i][j] = 0.f;

    for (int k0 = 0; k0 < DSPAN; k0 += 32) {
        __syncthreads();
        // stage svc_t (k-major): thread loads float4 of row r, scatters to 4 k-rows
        {
            int r = t >> 3, c4 = t & 7;
            float4 v = *(const float4*)(sv + (size_t)(n0 + r) * DSPAN + k0 + c4 * 4);
            svc_t[c4 * 4 + 0][r] = v.x;
            svc_t[c4 * 4 + 1][r] = v.y;
            svc_t[c4 * 4 + 2][r] = v.z;
            svc_t[c4 * 4 + 3][r] = v.w;
        }
        // stage w1c: 32 x 160, 20 per thread (zero-pad j>=150)
        #pragma unroll
        for (int i = 0; i < 20; ++i) {
            int idx = t + i * 256;
            int k = idx / HP, j = idx - (idx / HP) * HP;
            w1c[k][j] = (j < HH) ? W1[(size_t)(k0 + k) * HH + j] : 0.f;
        }
        __syncthreads();
        #pragma unroll
        for (int kk = 0; kk < 32; ++kk) {
            float4 a4 = *(const float4*)&svc_t[kk][r0];   // broadcast b128
            #pragma unroll
            for (int j = 0; j < 5; ++j) {
                float w = w1c[kk][j0 + j];
                acc[0][j] += a4.x * w;
                acc[1][j] += a4.y * w;
                acc[2][j] += a4.z * w;
                acc[3][j] += a4.w * w;
            }
        }
    }

    #pragma unroll
    for (int i = 0; i < 4; ++i)
        #pragma unroll
        for (int j = 0; j < 5; ++j) {
            int jj = j0 + j;
            if (jj < HH)
                out[(size_t)(n0 + r0 + i) * DMENT + DSPAN + jj] = acc[i][j] + b1[jj];
        }
}

// ---------------------------------------------------------------------------
// Kernel 2 (v2, MFMA): 16 spans/block (256 cand rows), 1024 blocks, 4 waves.
// Wave w owns row-tiles 4w..4w+3 (one span each). Per ks-step: 14 ds_read_b128
// feed 40 MFMAs. Per-acc K order and all fp32 epilogue orders identical to
// the validated version -> bit-identical output.
// ---------------------------------------------------------------------------
__global__ __launch_bounds__(256) void k2_mfma(const int*   __restrict__ cand,
                                               const float* __restrict__ mask,
                                               const float* __restrict__ emb,
                                               const unsigned short* __restrict__ Wt,
                                               const float* __restrict__ W2,
                                               float*       __restrict__ out) {
    const int b  = blockIdx.x;     // 1024 blocks
    const int t  = threadIdx.x;
    const int n0 = b * 16;
    const int w  = t >> 6;
    const int l  = t & 63;
    const int sp = l & 15;
    const int g  = l >> 4;

    __shared__ unsigned short A_lds[256][72];   // 256 rows x 64k chunk (pad->72)
    __shared__ unsigned short B_lds[160][72];
    __shared__ float hsL[16][HP];
    __shared__ float w2L[HP];
    __shared__ int   candL[256];
    __shared__ float maskL[256];
    __shared__ float scoresL[256];
    __shared__ float pL[256];

    candL[t] = cand[n0 * CC + t];
    maskL[t] = mask[n0 * CC + t];
    #pragma unroll
    for (int i = 0; i < 10; ++i) {              // 16*160 = 2560 = 10*256 exactly
        int idx = t + i * 256;
        int s = idx / HP, j = idx - (idx / HP) * HP;
        hsL[s][j] = (j < HH) ? out[(size_t)(n0 + s) * DMENT + DSPAN + j] : 0.f;
    }
    if (t < HP) w2L[t] = (t < HH) ? W2[t] : 0.f;
    __syncthreads();

    const float* asrc = emb + (size_t)candL[t] * DIM;   // this thread stages row t

    f32x4 acc[4][10];
    #pragma unroll
    for (int rt = 0; rt < 4; ++rt)
        #pragma unroll
        for (int nt = 0; nt < 10; ++nt) acc[rt][nt] = 0.f;

    for (int k0 = 0; k0 < KP; k0 += 64) {
        __syncthreads();
        // ---- stage A: thread t stages its row's 64-k slab, bf16-packed
        if (k0 + 64 <= DIM) {
            #pragma unroll
            for (int q = 0; q < 8; ++q) {
                float4 v0 = *(const float4*)(asrc + k0 + q * 8);
                float4 v1 = *(const float4*)(asrc + k0 + q * 8 + 4);
                uint4 p;
                p.x = f2bf(v0.x) | ((unsigned)f2bf(v0.y) << 16);
                p.y = f2bf(v0.z) | ((unsigned)f2bf(v0.w) << 16);
                p.z = f2bf(v1.x) | ((unsigned)f2bf(v1.y) << 16);
                p.w = f2bf(v1.z) | ((unsigned)f2bf(v1.w) << 16);
                *(uint4*)&A_lds[t][q * 8] = p;
            }
        } else {
            #pragma unroll
            for (int q = 0; q < 8; ++q) {
                unsigned short e[8];
                #pragma unroll
                for (int i2 = 0; i2 < 8; ++i2) {
                    int kg = k0 + q * 8 + i2;
                    e[i2] = (kg < DIM) ? f2bf(asrc[kg]) : (unsigned short)0;
                }
                uint4 p;
                p.x = e[0] | ((unsigned)e[1] << 16);
                p.y = e[2] | ((unsigned)e[3] << 16);
                p.z = e[4] | ((unsigned)e[5] << 16);
                p.w = e[6] | ((unsigned)e[7] << 16);
                *(uint4*)&A_lds[t][q * 8] = p;
            }
        }
        // ---- stage B: 160 rows x 8 segs of 8 shorts = 1280 segs, 5/thread
        #pragma unroll
        for (int i2 = 0; i2 < 5; ++i2) {
            int idx = t + i2 * 256;
            int row = idx >> 3, seg = idx & 7;
            uint4 v = *(const uint4*)(Wt + (size_t)row * KP + k0 + seg * 8);
            *(uint4*)&B_lds[row][seg * 8] = v;
        }
        __syncthreads();
        // ---- MFMA: per ks, 4 af + 10 bfr reads feed 40 MFMAs
        #pragma unroll
        for (int ks = 0; ks < 2; ++ks) {
            int koff = ks * 32 + g * 8;
            bf16x8 af[4];
            #pragma unroll
            for (int rt = 0; rt < 4; ++rt)
                af[rt] = *(const bf16x8*)&A_lds[w * 64 + rt * 16 + sp][koff];
            #pragma unroll
            for (int nt = 0; nt < 10; ++nt) {
                bf16x8 bfr = *(const bf16x8*)&B_lds[nt * 16 + sp][koff];
                #pragma unroll
                for (int rt = 0; rt < 4; ++rt)
                    acc[rt][nt] = __builtin_amdgcn_mfma_f32_16x16x32_bf16(af[rt], bfr, acc[rt][nt], 0, 0, 0);
            }
        }
    }

    // ---- scores: relu(acc + hs) . W2, reduce over sp within each 16-lane group
    #pragma unroll
    for (int rt = 0; rt < 4; ++rt) {
        int s = 4 * w + rt;
        float p0 = 0.f, p1 = 0.f, p2 = 0.f, p3 = 0.f;
        #pragma unroll
        for (int nt = 0; nt < 10; ++nt) {
            int col = nt * 16 + sp;
            float hb  = hsL[s][col];
            float w2v = w2L[col];
            p0 += fmaxf(acc[rt][nt][0] + hb, 0.f) * w2v;
            p1 += fmaxf(acc[rt][nt][1] + hb, 0.f) * w2v;
            p2 += fmaxf(acc[rt][nt][2] + hb, 0.f) * w2v;
            p3 += fmaxf(acc[rt][nt][3] + hb, 0.f) * w2v;
        }
        #pragma unroll
        for (int m = 1; m < 16; m <<= 1) {
            p0 += __shfl_xor(p0, m, 64);
            p1 += __shfl_xor(p1, m, 64);
            p2 += __shfl_xor(p2, m, 64);
            p3 += __shfl_xor(p3, m, 64);
        }
        if (sp == 0) {
            scoresL[s * 16 + g * 4 + 0] = p0;
            scoresL[s * 16 + g * 4 + 1] = p1;
            scoresL[s * 16 + g * 4 + 2] = p2;
            scoresL[s * 16 + g * 4 + 3] = p3;
        }
    }
    __syncthreads();

    // ---- masked softmax: 256 threads = 16 spans x 16 cands (16-lane groups)
    {
        float v = (maskL[t] > 0.f) ? scoresL[t] : -INFINITY;
        float mx = v;
        #pragma unroll
        for (int m = 1; m < 16; m <<= 1) mx = fmaxf(mx, __shfl_xor(mx, m, 64));
        float e = expf(v - mx);
        float sm = e;
        #pragma unroll
        for (int m = 1; m < 16; m <<= 1) sm += __shfl_xor(sm, m, 64);
        pL[t] = e / sm;
    }
    __syncthreads();

    // ---- weighted sum (fp32 exact), float4-vectorized: 16 spans x 75 f4
    for (int idx = t; idx < 16 * 75; idx += 256) {
        int s = idx / 75, q = idx - s * 75;
        float4 a = make_float4(0.f, 0.f, 0.f, 0.f);
        #pragma unroll
        for (int c = 0; c < CC; ++c) {
            float p = pL[s * CC + c];
            float4 v = *(const float4*)(emb + (size_t)candL[s * CC + c] * DIM + q * 4);
            a.x += p * v.x; a.y += p * v.y; a.z += p * v.z; a.w += p * v.w;
        }
        *(float4*)(out + (size_t)(n0 + s) * DMENT + DSPAN + q * 4) = a;
    }
}

extern "C" void kernel_launch(void* const* d_in, const int* in_sizes, int n_in,
                              void* d_out, int out_size, void* d_ws, size_t ws_size,
                              hipStream_t stream) {
    const float* sv   = (const float*)d_in[0];
    const int*   cand = (const int*)d_in[1];
    const float* mask = (const float*)d_in[2];
    const float* emb  = (const float*)d_in[3];
    const float* W1   = (const float*)d_in[4];
    const float* b1   = (const float*)d_in[5];
    const float* W2   = (const float*)d_in[6];
    // b2 (d_in[7]) is softmax-invariant -> dropped
    float* out = (float*)d_out;
    unsigned short* Wt = (unsigned short*)d_ws;   // 160*320*2 = 102400 B

    k0_prep<<<(HP * KP) / 256, 256, 0, stream>>>(W1, Wt);
    k1_span<<<NSPANS / 32, 256, 0, stream>>>(sv, W1, b1, out);
    k2_mfma<<<NSPANS / 16, 256, 0, stream>>>(cand, mask, emb, Wt, W2, out);
}

// Round 8
// 628.057 us; speedup vs baseline: 1.1489x; 1.0498x over previous
//
#include <hip/hip_runtime.h>
#include <hip/hip_bf16.h>
#include <math.h>

#define NSPANS 16384
#define CC     16
#define DIM    300
#define DSPAN  512
#define HH     150
#define HP     160     // padded H
#define DMENT  812     // DSPAN + DIM
#define KP     320     // padded K for candidate GEMM (300 -> 320)
#define BSTR   328     // B_lds row stride in shorts (656 B = 4-bank row step)

typedef short bf16x8 __attribute__((ext_vector_type(8)));
typedef float f32x4  __attribute__((ext_vector_type(4)));

__device__ __forceinline__ unsigned short f2bf(float f) {
    union { float f; unsigned int u; } v; v.f = f;
    unsigned int r = (v.u + 0x7FFFu + ((v.u >> 16) & 1u)) >> 16;   // RNE (no NaN inputs)
    return (unsigned short)r;
}

// ---------------------------------------------------------------------------
// Kernel 0 (prep): W1_bot [300x150] f32 -> Wt [160x320] bf16 transposed.
// ---------------------------------------------------------------------------
__global__ __launch_bounds__(256) void k0_prep(const float* __restrict__ W1,
                                               unsigned short* __restrict__ Wt) {
    int idx = blockIdx.x * 256 + threadIdx.x;          // 200 blocks = 51200
    int n = idx / KP, k = idx - n * KP;
    float v = (n < HH && k < DIM) ? W1[(size_t)(DSPAN + k) * HH + n] : 0.f;
    Wt[idx] = f2bf(v);
}

// ---------------------------------------------------------------------------
// Kernel 1 (unchanged v2): 32 spans/block. hs bit-identical to validated.
// ---------------------------------------------------------------------------
__global__ __launch_bounds__(256) void k1_span(const float* __restrict__ sv,
                                               const float* __restrict__ W1,
                                               const float* __restrict__ b1,
                                               float* __restrict__ out) {
    const int b  = blockIdx.x;     // 512 blocks
    const int t  = threadIdx.x;
    const int n0 = b * 32;

    __shared__ float svc_t[32][36];   // [k][row]
    __shared__ float w1c[32][HP];

    #pragma unroll
    for (int i = 0; i < 16; ++i) {
        int idx4 = t + i * 256;
        int r = idx4 >> 7, c4 = idx4 & 127;
        float4 v = *(const float4*)(sv + (size_t)(n0 + r) * DSPAN + c4 * 4);
        *(float4*)(out + (size_t)(n0 + r) * DMENT + c4 * 4) = v;
    }

    const int tc = t & 31;
    const int tr = t >> 5;
    const int j0 = tc * 5;
    const int r0 = tr * 4;

    float acc[4][5];
    #pragma unroll
    for (int i = 0; i < 4; ++i)
        #pragma unroll
        for (int j = 0; j < 5; ++j) acc[i][j] = 0.f;

    for (int k0 = 0; k0 < DSPAN; k0 += 32) {
        __syncthreads();
        {
            int r = t >> 3, c4 = t & 7;
            float4 v = *(const float4*)(sv + (size_t)(n0 + r) * DSPAN + k0 + c4 * 4);
            svc_t[c4 * 4 + 0][r] = v.x;
            svc_t[c4 * 4 + 1][r] = v.y;
            svc_t[c4 * 4 + 2][r] = v.z;
            svc_t[c4 * 4 + 3][r] = v.w;
        }
        #pragma unroll
        for (int i = 0; i < 20; ++i) {
            int idx = t + i * 256;
            int k = idx / HP, j = idx - (idx / HP) * HP;
            w1c[k][j] = (j < HH) ? W1[(size_t)(k0 + k) * HH + j] : 0.f;
        }
        __syncthreads();
        #pragma unroll
        for (int kk = 0; kk < 32; ++kk) {
            float4 a4 = *(const float4*)&svc_t[kk][r0];
            #pragma unroll
            for (int j = 0; j < 5; ++j) {
                float w = w1c[kk][j0 + j];
                acc[0][j] += a4.x * w;
                acc[1][j] += a4.y * w;
                acc[2][j] += a4.z * w;
                acc[3][j] += a4.w * w;
            }
        }
    }

    #pragma unroll
    for (int i = 0; i < 4; ++i)
        #pragma unroll
        for (int j = 0; j < 5; ++j) {
            int jj = j0 + j;
            if (jj < HH)
                out[(size_t)(n0 + r0 + i) * DMENT + DSPAN + jj] = acc[i][j] + b1[jj];
        }
}

// ---------------------------------------------------------------------------
// Kernel 2 (v3, MFMA): wave-per-span, 8 spans/block, 2048 blocks.
// A-fragments loaded DIRECTLY from global (lane (sp,g) reads row cand[sp],
// k=kt*32+g*8..+8) -- all 20 float4 gather loads issued up front; B (Wt)
// staged to LDS once per block; K-loop has no barriers. Softmax in-wave.
// MFMA per-acc K order, relu/score/exp orders unchanged -> numerics ==
// validated version (softmax reduce tree reassociated: exact max, sum
// differs by <1 ulp).
// ---------------------------------------------------------------------------
__global__ __launch_bounds__(512) void k2_mfma(const int*   __restrict__ cand,
                                               const float* __restrict__ mask,
                                               const float* __restrict__ emb,
                                               const unsigned short* __restrict__ Wt,
                                               const float* __restrict__ W2,
                                               float*       __restrict__ out) {
    const int b  = blockIdx.x;     // 2048 blocks
    const int t  = threadIdx.x;    // 512 threads = 8 waves
    const int n0 = b * 8;
    const int w  = t >> 6;         // wave = span within block
    const int l  = t & 63;
    const int sp = l & 15;         // A row (candidate) / B col
    const int g  = l >> 4;         // k-group

    __shared__ unsigned short B_lds[160][BSTR];   // 105 KB
    __shared__ float hsL[8][HP];
    __shared__ float w2L[HP];
    __shared__ int   candL[128];
    __shared__ float maskL[128];
    __shared__ float pL[8][16];

    if (t < 128) {
        candL[t] = cand[n0 * CC + t];
        maskL[t] = mask[n0 * CC + t];
    }
    for (int idx = t; idx < 8 * HP; idx += 512) {
        int s = idx / HP, j = idx - s * HP;
        hsL[s][j] = (j < HH) ? out[(size_t)(n0 + s) * DMENT + DSPAN + j] : 0.f;
    }
    if (t < HP) w2L[t] = (t < HH) ? W2[t] : 0.f;
    // stage B once: 160 rows x 40 segs of 16B
    for (int idx = t; idx < 6400; idx += 512) {
        int row = idx / 40, seg = idx - row * 40;
        uint4 v = *(const uint4*)(Wt + (size_t)row * KP + seg * 8);
        *(uint4*)&B_lds[row][seg * 8] = v;
    }
    __syncthreads();

    const float* asrc = emb + (size_t)candL[w * 16 + sp] * DIM;

    // ---- issue ALL gather loads up front (20 x float4 per lane)
    float4 a[10][2];
    #pragma unroll
    for (int kt = 0; kt < 10; ++kt)
        #pragma unroll
        for (int h = 0; h < 2; ++h) {
            int kb = kt * 32 + g * 8 + h * 4;
            a[kt][h] = (kb < DIM) ? *(const float4*)(asrc + kb)
                                  : make_float4(0.f, 0.f, 0.f, 0.f);
        }

    f32x4 acc[10];
    #pragma unroll
    for (int nt = 0; nt < 10; ++nt) acc[nt] = 0.f;

    // ---- barrier-free K loop: cvt + 10 ds_read_b128 + 10 MFMA per kt
    #pragma unroll
    for (int kt = 0; kt < 10; ++kt) {
        union { uint4 u; bf16x8 h; } cv;
        cv.u.x = f2bf(a[kt][0].x) | ((unsigned)f2bf(a[kt][0].y) << 16);
        cv.u.y = f2bf(a[kt][0].z) | ((unsigned)f2bf(a[kt][0].w) << 16);
        cv.u.z = f2bf(a[kt][1].x) | ((unsigned)f2bf(a[kt][1].y) << 16);
        cv.u.w = f2bf(a[kt][1].z) | ((unsigned)f2bf(a[kt][1].w) << 16);
        bf16x8 af = cv.h;
        const int koff = kt * 32 + g * 8;
        #pragma unroll
        for (int nt = 0; nt < 10; ++nt) {
            bf16x8 bfr = *(const bf16x8*)&B_lds[nt * 16 + sp][koff];
            acc[nt] = __builtin_amdgcn_mfma_f32_16x16x32_bf16(af, bfr, acc[nt], 0, 0, 0);
        }
    }

    // ---- scores: relu(acc + hs) . W2 ; lane holds rows g*4+reg, col sp
    float s0 = 0.f, s1 = 0.f, s2 = 0.f, s3 = 0.f;
    #pragma unroll
    for (int nt = 0; nt < 10; ++nt) {
        int col = nt * 16 + sp;
        float hb  = hsL[w][col];
        float w2v = w2L[col];
        s0 += fmaxf(acc[nt][0] + hb, 0.f) * w2v;
        s1 += fmaxf(acc[nt][1] + hb, 0.f) * w2v;
        s2 += fmaxf(acc[nt][2] + hb, 0.f) * w2v;
        s3 += fmaxf(acc[nt][3] + hb, 0.f) * w2v;
    }
    #pragma unroll
    for (int m = 1; m < 16; m <<= 1) {
        s0 += __shfl_xor(s0, m, 64);
        s1 += __shfl_xor(s1, m, 64);
        s2 += __shfl_xor(s2, m, 64);
        s3 += __shfl_xor(s3, m, 64);
    }

    // ---- in-wave masked softmax over the 16 candidates of span w
    float v0 = (maskL[w * 16 + g * 4 + 0] > 0.f) ? s0 : -INFINITY;
    float v1 = (maskL[w * 16 + g * 4 + 1] > 0.f) ? s1 : -INFINITY;
    float v2 = (maskL[w * 16 + g * 4 + 2] > 0.f) ? s2 : -INFINITY;
    float v3 = (maskL[w * 16 + g * 4 + 3] > 0.f) ? s3 : -INFINITY;
    float mx = fmaxf(fmaxf(v0, v1), fmaxf(v2, v3));
    mx = fmaxf(mx, __shfl_xor(mx, 16, 64));
    mx = fmaxf(mx, __shfl_xor(mx, 32, 64));
    float e0 = expf(v0 - mx), e1 = expf(v1 - mx), e2 = expf(v2 - mx), e3 = expf(v3 - mx);
    float sm = (e0 + e1) + (e2 + e3);
    sm += __shfl_xor(sm, 16, 64);
    sm += __shfl_xor(sm, 32, 64);
    if (sp == 0) {
        pL[w][g * 4 + 0] = e0 / sm;
        pL[w][g * 4 + 1] = e1 / sm;
        pL[w][g * 4 + 2] = e2 / sm;
        pL[w][g * 4 + 3] = e3 / sm;
    }
    __syncthreads();

    // ---- weighted sum (fp32 exact): wave handles its span; L2-hot rows
    float pr[16];
    const float* rp[16];
    #pragma unroll
    for (int c = 0; c < CC; ++c) {
        pr[c] = pL[w][c];
        rp[c] = emb + (size_t)candL[w * 16 + c] * DIM;
    }
    for (int q = l; q < 75; q += 64) {
        float4 acc4 = make_float4(0.f, 0.f, 0.f, 0.f);
        #pragma unroll
        for (int c = 0; c < CC; ++c) {
            float p = pr[c];
            float4 v = *(const float4*)(rp[c] + q * 4);
            acc4.x += p * v.x; acc4.y += p * v.y; acc4.z += p * v.z; acc4.w += p * v.w;
        }
        *(float4*)(out + (size_t)(n0 + w) * DMENT + DSPAN + q * 4) = acc4;
    }
}

extern "C" void kernel_launch(void* const* d_in, const int* in_sizes, int n_in,
                              void* d_out, int out_size, void* d_ws, size_t ws_size,
                              hipStream_t stream) {
    const float* sv   = (const float*)d_in[0];
    const int*   cand = (const int*)d_in[1];
    const float* mask = (const float*)d_in[2];
    const float* emb  = (const float*)d_in[3];
    const float* W1   = (const float*)d_in[4];
    const float* b1   = (const float*)d_in[5];
    const float* W2   = (const float*)d_in[6];
    // b2 (d_in[7]) is softmax-invariant -> dropped
    float* out = (float*)d_out;
    unsigned short* Wt = (unsigned short*)d_ws;   // 160*320*2 = 102400 B

    k0_prep<<<(HP * KP) / 256, 256, 0, stream>>>(W1, Wt);
    k1_span<<<NSPANS / 32, 256, 0, stream>>>(sv, W1, b1, out);
    k2_mfma<<<NSPANS / 8, 512, 0, stream>>>(cand, mask, emb, Wt, W2, out);
}

// Round 11
// 586.256 us; speedup vs baseline: 1.2308x; 1.0713x over previous
//
#include <hip/hip_runtime.h>
#include <hip/hip_bf16.h>
#include <math.h>

#define NSPANS 16384
#define CC     16
#define DIM    300
#define DSPAN  512
#define HH     150
#define HP     160     // padded H
#define DMENT  812     // DSPAN + DIM
#define KP     320     // padded K for candidate GEMM (300 -> 320)
#define BSTR   328     // B_lds row stride in shorts (656 B -> 2-way banks, free)

typedef short bf16x8 __attribute__((ext_vector_type(8)));
typedef float f32x4  __attribute__((ext_vector_type(4)));

__device__ __forceinline__ unsigned short f2bf(float f) {
    union { float f; unsigned int u; } v; v.f = f;
    unsigned int r = (v.u + 0x7FFFu + ((v.u >> 16) & 1u)) >> 16;   // RNE (no NaN inputs)
    return (unsigned short)r;
}

// ---------------------------------------------------------------------------
// Kernel 0 (prep): W1_bot [300x150] f32 -> Wt [160x320] bf16 transposed.
// ---------------------------------------------------------------------------
__global__ __launch_bounds__(256) void k0_prep(const float* __restrict__ W1,
                                               unsigned short* __restrict__ Wt) {
    int idx = blockIdx.x * 256 + threadIdx.x;          // 200 blocks = 51200
    int n = idx / KP, k = idx - n * KP;
    float v = (n < HH && k < DIM) ? W1[(size_t)(DSPAN + k) * HH + n] : 0.f;
    Wt[idx] = f2bf(v);
}

// ---------------------------------------------------------------------------
// Kernel 1 (v4, split-K teams): 512 blocks x 512 threads (2 teams of 256).
// Team h computes the K-half [h*256, h*256+256) with the acc[4][5] register
// tile over 32 spans; partials combined through LDS. One fp32 reassociation
// (sum0+sum1) vs the validated sequential order -> hs differs by ~1e-7 rel.
// ---------------------------------------------------------------------------
__global__ __launch_bounds__(512) void k1_span(const float* __restrict__ sv,
                                               const float* __restrict__ W1,
                                               const float* __restrict__ b1,
                                               float* __restrict__ out) {
    const int b  = blockIdx.x;     // 512 blocks
    const int t  = threadIdx.x;    // 512 threads
    const int n0 = b * 32;
    const int team = t >> 8;       // 0: k<256, 1: k>=256
    const int u    = t & 255;

    __shared__ float svc_t[2][32][36];    // [team][k][row]
    __shared__ float w1c[2][32][HP];      // [team][k][col]
    __shared__ float partial[32][HP];     // team1 -> team0

    // copy sv -> out: 32 rows x 128 float4 = 4096, 8 per thread
    #pragma unroll
    for (int i = 0; i < 8; ++i) {
        int idx4 = t + i * 512;
        int r = idx4 >> 7, c4 = idx4 & 127;
        float4 v = *(const float4*)(sv + (size_t)(n0 + r) * DSPAN + c4 * 4);
        *(float4*)(out + (size_t)(n0 + r) * DMENT + c4 * 4) = v;
    }

    const int tc = u & 31;          // 32 col groups x 5 cols
    const int tr = u >> 5;          // 8 row groups x 4 rows
    const int j0 = tc * 5;
    const int r0 = tr * 4;
    const int kbase = team * 256;

    float acc[4][5];
    #pragma unroll
    for (int i = 0; i < 4; ++i)
        #pragma unroll
        for (int j = 0; j < 5; ++j) acc[i][j] = 0.f;

    for (int k0 = 0; k0 < 256; k0 += 32) {
        __syncthreads();
        // stage svc_t (k-major): thread loads float4 of row r, scatters 4 k-rows
        {
            int r = u >> 3, c4 = u & 7;
            float4 v = *(const float4*)(sv + (size_t)(n0 + r) * DSPAN + kbase + k0 + c4 * 4);
            svc_t[team][c4 * 4 + 0][r] = v.x;
            svc_t[team][c4 * 4 + 1][r] = v.y;
            svc_t[team][c4 * 4 + 2][r] = v.z;
            svc_t[team][c4 * 4 + 3][r] = v.w;
        }
        // stage w1c: 32 x 160, 20 per thread (zero-pad j>=150)
        #pragma unroll
        for (int i = 0; i < 20; ++i) {
            int idx = u + i * 256;
            int k = idx / HP, j = idx - (idx / HP) * HP;
            w1c[team][k][j] = (j < HH) ? W1[(size_t)(kbase + k0 + k) * HH + j] : 0.f;
        }
        __syncthreads();
        #pragma unroll
        for (int kk = 0; kk < 32; ++kk) {
            float4 a4 = *(const float4*)&svc_t[team][kk][r0];
            #pragma unroll
            for (int j = 0; j < 5; ++j) {
                float w = w1c[team][kk][j0 + j];
                acc[0][j] += a4.x * w;
                acc[1][j] += a4.y * w;
                acc[2][j] += a4.z * w;
                acc[3][j] += a4.w * w;
            }
        }
    }

    // combine: team1 publishes partial, team0 adds + bias + store
    if (team == 1) {
        #pragma unroll
        for (int i = 0; i < 4; ++i)
            #pragma unroll
            for (int j = 0; j < 5; ++j)
                partial[r0 + i][j0 + j] = acc[i][j];
    }
    __syncthreads();
    if (team == 0) {
        #pragma unroll
        for (int i = 0; i < 4; ++i)
            #pragma unroll
            for (int j = 0; j < 5; ++j) {
                int jj = j0 + j;
                if (jj < HH)
                    out[(size_t)(n0 + r0 + i) * DMENT + DSPAN + jj] =
                        (acc[i][j] + partial[r0 + i][jj]) + b1[jj];
            }
    }
}

// ---------------------------------------------------------------------------
// Kernel 2 (v4, MFMA): 1024 blocks x 1024 threads (16 waves), wave-per-span.
// B (Wt) staged once per 16 spans; barrier-free K loop with a 2-deep global
// prefetch pipeline for the A gather (16 waves/CU keep ~64 KB/CU in flight).
// Per-acc K order, relu/score/softmax/weighted-sum orders identical to the
// validated version.
// ---------------------------------------------------------------------------
__global__ __launch_bounds__(1024) void k2_mfma(const int*   __restrict__ cand,
                                                const float* __restrict__ mask,
                                                const float* __restrict__ emb,
                                                const unsigned short* __restrict__ Wt,
                                                const float* __restrict__ W2,
                                                float*       __restrict__ out) {
    const int b  = blockIdx.x;     // 1024 blocks
    const int t  = threadIdx.x;    // 1024 threads = 16 waves
    const int n0 = b * 16;
    const int w  = t >> 6;         // wave = span within block
    const int l  = t & 63;
    const int sp = l & 15;         // A row (candidate) / B col
    const int g  = l >> 4;         // k-group

    __shared__ unsigned short B_lds[160][BSTR];   // 105 KB
    __shared__ float hsL[16][HP];
    __shared__ float w2L[HP];
    __shared__ int   candL[256];
    __shared__ float maskL[256];
    __shared__ float pL[16][16];

    if (t < 256) {
        candL[t] = cand[n0 * CC + t];
        maskL[t] = mask[n0 * CC + t];
    }
    for (int idx = t; idx < 16 * HP; idx += 1024) {
        int s = idx / HP, j = idx - s * HP;
        hsL[s][j] = (j < HH) ? out[(size_t)(n0 + s) * DMENT + DSPAN + j] : 0.f;
    }
    if (t < HP) w2L[t] = (t < HH) ? W2[t] : 0.f;
    for (int idx = t; idx < 6400; idx += 1024) {
        int row = idx / 40, seg = idx - (idx / 40) * 40;
        uint4 v = *(const uint4*)(Wt + (size_t)row * KP + seg * 8);
        *(uint4*)&B_lds[row][seg * 8] = v;
    }
    __syncthreads();

    const float* asrc = emb + (size_t)candL[w * 16 + sp] * DIM;

    // 2-deep prefetch pipeline
    float4 abuf[2][2];
    #pragma unroll
    for (int h = 0; h < 2; ++h) {
        abuf[0][h] = *(const float4*)(asrc + g * 8 + h * 4);
        abuf[1][h] = *(const float4*)(asrc + 32 + g * 8 + h * 4);
    }

    f32x4 acc[10];
    #pragma unroll
    for (int nt = 0; nt < 10; ++nt) acc[nt] = 0.f;

    #pragma unroll
    for (int kt = 0; kt < 10; ++kt) {
        const int cur = kt & 1;
        union { uint4 u; bf16x8 h8; } cv;
        cv.u.x = f2bf(abuf[cur][0].x) | ((unsigned)f2bf(abuf[cur][0].y) << 16);
        cv.u.y = f2bf(abuf[cur][0].z) | ((unsigned)f2bf(abuf[cur][0].w) << 16);
        cv.u.z = f2bf(abuf[cur][1].x) | ((unsigned)f2bf(abuf[cur][1].y) << 16);
        cv.u.w = f2bf(abuf[cur][1].z) | ((unsigned)f2bf(abuf[cur][1].w) << 16);
        bf16x8 af = cv.h8;
        if (kt + 2 < 10) {
            #pragma unroll
            for (int h = 0; h < 2; ++h) {
                int kb = (kt + 2) * 32 + g * 8 + h * 4;
                abuf[cur][h] = (kb < DIM) ? *(const float4*)(asrc + kb)
                                          : make_float4(0.f, 0.f, 0.f, 0.f);
            }
        }
        const int koff = kt * 32 + g * 8;
        #pragma unroll
        for (int nt = 0; nt < 10; ++nt) {
            bf16x8 bfr = *(const bf16x8*)&B_lds[nt * 16 + sp][koff];
            acc[nt] = __builtin_amdgcn_mfma_f32_16x16x32_bf16(af, bfr, acc[nt], 0, 0, 0);
        }
    }

    // ---- scores: relu(acc + hs) . W2 ; lane holds rows g*4+reg, col sp
    float s0 = 0.f, s1 = 0.f, s2 = 0.f, s3 = 0.f;
    #pragma unroll
    for (int nt = 0; nt < 10; ++nt) {
        int col = nt * 16 + sp;
        float hb  = hsL[w][col];
        float w2v = w2L[col];
        s0 += fmaxf(acc[nt][0] + hb, 0.f) * w2v;
        s1 += fmaxf(acc[nt][1] + hb, 0.f) * w2v;
        s2 += fmaxf(acc[nt][2] + hb, 0.f) * w2v;
        s3 += fmaxf(acc[nt][3] + hb, 0.f) * w2v;
    }
    #pragma unroll
    for (int m = 1; m < 16; m <<= 1) {
        s0 += __shfl_xor(s0, m, 64);
        s1 += __shfl_xor(s1, m, 64);
        s2 += __shfl_xor(s2, m, 64);
        s3 += __shfl_xor(s3, m, 64);
    }

    // ---- in-wave masked softmax over the 16 candidates of span w
    float v0 = (maskL[w * 16 + g * 4 + 0] > 0.f) ? s0 : -INFINITY;
    float v1 = (maskL[w * 16 + g * 4 + 1] > 0.f) ? s1 : -INFINITY;
    float v2 = (maskL[w * 16 + g * 4 + 2] > 0.f) ? s2 : -INFINITY;
    float v3 = (maskL[w * 16 + g * 4 + 3] > 0.f) ? s3 : -INFINITY;
    float mx = fmaxf(fmaxf(v0, v1), fmaxf(v2, v3));
    mx = fmaxf(mx, __shfl_xor(mx, 16, 64));
    mx = fmaxf(mx, __shfl_xor(mx, 32, 64));
    float e0 = expf(v0 - mx), e1 = expf(v1 - mx), e2 = expf(v2 - mx), e3 = expf(v3 - mx);
    float sm = (e0 + e1) + (e2 + e3);
    sm += __shfl_xor(sm, 16, 64);
    sm += __shfl_xor(sm, 32, 64);
    if (sp == 0) {
        pL[w][g * 4 + 0] = e0 / sm;
        pL[w][g * 4 + 1] = e1 / sm;
        pL[w][g * 4 + 2] = e2 / sm;
        pL[w][g * 4 + 3] = e3 / sm;
    }
    // per-wave pL RAW: same-wave LDS ordering via lgkmcnt (compiler-inserted);
    // no block barrier needed -- waves proceed independently.

    // ---- weighted sum (fp32 exact): wave handles its span; rows L2-hot
    for (int q = l; q < 75; q += 64) {
        float4 a4 = make_float4(0.f, 0.f, 0.f, 0.f);
        #pragma unroll
        for (int c = 0; c < CC; ++c) {
            float p = pL[w][c];
            const float* rp = emb + (size_t)candL[w * 16 + c] * DIM;
            float4 v = *(const float4*)(rp + q * 4);
            a4.x += p * v.x; a4.y += p * v.y; a4.z += p * v.z; a4.w += p * v.w;
        }
        *(float4*)(out + (size_t)(n0 + w) * DMENT + DSPAN + q * 4) = a4;
    }
}

extern "C" void kernel_launch(void* const* d_in, const int* in_sizes, int n_in,
                              void* d_out, int out_size, void* d_ws, size_t ws_size,
                              hipStream_t stream) {
    const float* sv   = (const float*)d_in[0];
    const int*   cand = (const int*)d_in[1];
    const float* mask = (const float*)d_in[2];
    const float* emb  = (const float*)d_in[3];
    const float* W1   = (const float*)d_in[4];
    const float* b1   = (const float*)d_in[5];
    const float* W2   = (const float*)d_in[6];
    // b2 (d_in[7]) is softmax-invariant -> dropped
    float* out = (float*)d_out;
    unsigned short* Wt = (unsigned short*)d_ws;   // 160*320*2 = 102400 B

    k0_prep<<<(HP * KP) / 256, 256, 0, stream>>>(W1, Wt);
    k1_span<<<NSPANS / 32, 512, 0, stream>>>(sv, W1, b1, out);
    k2_mfma<<<NSPANS / 16, 1024, 0, stream>>>(cand, mask, emb, Wt, W2, out);
}